// Round 3
// baseline (141.736 us; speedup 1.0000x reference)
//
#include <hip/hip_runtime.h>

// RankLoss via triangle formulation + poly-log:
//   per unordered pair {i,j}: contribution = min(sd,0) - ln(1+e^{-|d|}),
//   d = p[i]-p[j], sd = (t[i]<t[j] ? d : -d).  count = C(8192,2) analytic.
// ln(1+u) on [0,1] replaced by u*q(u) + B0 (Chebyshev-derived, |err|<=1.5e-5);
// the B0*count constant is folded into the final division.

#define N 8192
#define TI 128
#define NB (N / TI)                  // 64
#define NTILES (NB * (NB + 1) / 2)   // 2080

// ln(1+u) ~= B0 + u*(B1 + u*(B2 + u*(B3 + u*(B4 + u*B5)))),  u in [0,1]
#define B0 (-1.084e-05f)
#define B1 ( 0.99923144f)
#define B2 (-0.49021708f)
#define B3 ( 0.28525664f)
#define B4 (-0.13157376f)
#define B5 ( 0.03044704f)

struct Accums { float st; float sl; unsigned int ticket; unsigned int pad; };

__global__ __launch_bounds__(TI) void rankloss_tri(
    const float* __restrict__ preds, const float* __restrict__ tgts,
    Accums* __restrict__ acc, float* __restrict__ out)
{
    __shared__ float2 sj[TI];
    const int tid = threadIdx.x;
    const int u = blockIdx.x;

    // decode triangular tile index: u = jb*(jb+1)/2 + ib, ib <= jb
    int jb = (int)((sqrtf(8.0f * (float)u + 1.0f) - 1.0f) * 0.5f);
    while ((jb + 1) * (jb + 2) / 2 <= u) ++jb;
    while (jb * (jb + 1) / 2 > u) --jb;
    const int ib = u - jb * (jb + 1) / 2;

    const int i  = ib * TI + tid;
    const int j0 = jb * TI;

    sj[tid] = make_float2(preds[j0 + tid], tgts[j0 + tid]);
    __syncthreads();

    const float pi = preds[i];
    const float ti = tgts[i];

    float st = 0.f;   // sum of min(sd, 0)
    float sl = 0.f;   // sum of u*q(u)  (= ln(1+u) - B0 per pair)

    if (ib != jb) {
        #pragma unroll 8
        for (int k = 0; k < TI; ++k) {
            const float2 jt = sj[k];          // consecutive float2 -> ds_read_b128 pairs
            const float d  = pi - jt.x;
            const float eu = __expf(-fabsf(d));
            float q = B5;
            q = __builtin_fmaf(q, eu, B4);
            q = __builtin_fmaf(q, eu, B3);
            q = __builtin_fmaf(q, eu, B2);
            q = __builtin_fmaf(q, eu, B1);
            sl = __builtin_fmaf(q, eu, sl);
            const float sd = (ti < jt.y) ? d : -d;
            st += fminf(sd, 0.0f);
        }
    } else {
        // diagonal tile: only k > tid (i < j) valid; masked lanes contribute 0
        #pragma unroll 8
        for (int k = 0; k < TI; ++k) {
            const float2 jt = sj[k];
            const float d  = pi - jt.x;
            float eu = __expf(-fabsf(d));
            float sd = fminf((ti < jt.y) ? d : -d, 0.0f);
            const bool valid = (k > tid);
            eu = valid ? eu : 0.0f;    // u=0 -> u*q(u)=0, no B-leak
            sd = valid ? sd : 0.0f;
            float q = B5;
            q = __builtin_fmaf(q, eu, B4);
            q = __builtin_fmaf(q, eu, B3);
            q = __builtin_fmaf(q, eu, B2);
            q = __builtin_fmaf(q, eu, B1);
            sl = __builtin_fmaf(q, eu, sl);
            st += sd;
        }
    }

    // wave(64) reduction, then block, then one atomic pair per block
    for (int off = 32; off > 0; off >>= 1) {
        st += __shfl_down(st, off, 64);
        sl += __shfl_down(sl, off, 64);
    }
    __shared__ float wt[TI / 64], wl[TI / 64];
    const int wave = tid >> 6;
    if ((tid & 63) == 0) { wt[wave] = st; wl[wave] = sl; }
    __syncthreads();

    if (tid == 0) {
        atomicAdd(&acc->st, wt[0] + wt[1]);
        atomicAdd(&acc->sl, wl[0] + wl[1]);
        __threadfence();
        const unsigned int old = atomicAdd(&acc->ticket, 1u);
        if (old == NTILES - 1) {
            // all blocks' adds are visible (threadfence before each ticket inc);
            // read via RMW for coherence
            const float St = atomicAdd(&acc->st, 0.0f);
            const float Sl = atomicAdd(&acc->sl, 0.0f);
            const double count = 33550336.0;  // C(8192,2)
            out[0] = (float)(((double)St - (double)Sl - (double)B0 * count) / count);
        }
    }
}

extern "C" void kernel_launch(void* const* d_in, const int* in_sizes, int n_in,
                              void* d_out, int out_size, void* d_ws, size_t ws_size,
                              hipStream_t stream) {
    const float* preds = (const float*)d_in[0];
    const float* tgts  = (const float*)d_in[1];

    hipMemsetAsync(d_ws, 0, sizeof(Accums), stream);  // zero st/sl/ticket
    rankloss_tri<<<NTILES, TI, 0, stream>>>(preds, tgts, (Accums*)d_ws, (float*)d_out);
}

// Round 4
// 72.505 us; speedup vs baseline: 1.9548x; 1.9548x over previous
//
#include <hip/hip_runtime.h>

// RankLoss, triangle + poly-log, log2-domain:
//   per unordered pair {i,j}: logsig = min(sd,0) - ln(1+e^{-|d|}),
//   d = p[i]-p[j], sd = (t[i]<t[j] ? d : -d).
// Work in d' = d*log2e: u = e^{-|d|} = 2^{-|d'|} (v_exp_f32, neg modifier free),
// min(sd,0) = ln2 * min(sd',0)  (ln2 folded into finalize).
// ln(1+u) ~= B0 + u*q(u) on [0,1], |err|<=1.5e-5; B0*count folded into finalize.
// count = C(8192,2) analytic (ties measure-zero for continuous targets).

#define N 8192
#define TI 128
#define NB (N / TI)                  // 64
#define NTILES (NB * (NB + 1) / 2)   // 2080
#define LOG2E 1.4426950408889634f

#define B0 (-1.084e-05f)
#define B1 ( 0.99923144f)
#define B2 (-0.49021708f)
#define B3 ( 0.28525664f)
#define B4 (-0.13157376f)
#define B5 ( 0.03044704f)

__device__ __forceinline__ void pair_term(float pip, float ti, float pj, float tj,
                                          bool valid, float& st, float& sl)
{
    const float dp = pip - pj;                      // d' = d*log2e
    const float a  = fabsf(dp);
    float u = __builtin_amdgcn_exp2f(-a);           // e^{-|d|}
    float sd = fminf((ti < tj) ? dp : -dp, 0.0f);   // min(sd',0)
    u  = valid ? u  : 0.0f;                         // u=0 -> u*q(u)=0
    sd = valid ? sd : 0.0f;
    float q = __builtin_fmaf(B5, u, B4);
    q = __builtin_fmaf(q, u, B3);
    q = __builtin_fmaf(q, u, B2);
    q = __builtin_fmaf(q, u, B1);
    sl = __builtin_fmaf(q, u, sl);                  // += u*q(u)
    st += sd;
}

__global__ __launch_bounds__(TI) void rankloss_tri(
    const float* __restrict__ preds, const float* __restrict__ tgts,
    float2* __restrict__ pout)
{
    __shared__ float2 s2[TI];   // {p*log2e, t} interleaved -> float4 reads
    const int tid = threadIdx.x;
    const int u = blockIdx.x;

    // decode triangular tile index: u = jb*(jb+1)/2 + ib, ib <= jb
    int jb = (int)((sqrtf(8.0f * (float)u + 1.0f) - 1.0f) * 0.5f);
    while ((jb + 1) * (jb + 2) / 2 <= u) ++jb;
    while (jb * (jb + 1) / 2 > u) --jb;
    const int ib = u - jb * (jb + 1) / 2;

    const int i  = ib * TI + tid;
    const int j0 = jb * TI;

    s2[tid] = make_float2(preds[j0 + tid] * LOG2E, tgts[j0 + tid]);
    __syncthreads();

    const float pip = preds[i] * LOG2E;
    const float ti  = tgts[i];

    float st = 0.f;   // sum of min(sd',0)
    float sl = 0.f;   // sum of u*q(u)

    const float4* s4 = (const float4*)s2;

    if (ib != jb) {
        #pragma unroll 4
        for (int kk = 0; kk < TI / 2; ++kk) {
            const float4 v = s4[kk];    // uniform addr -> LDS broadcast b128
            pair_term(pip, ti, v.x, v.y, true, st, sl);
            pair_term(pip, ti, v.z, v.w, true, st, sl);
        }
    } else {
        // diagonal tile: only j = k > i = tid contributes
        #pragma unroll 4
        for (int kk = 0; kk < TI / 2; ++kk) {
            const float4 v = s4[kk];
            pair_term(pip, ti, v.x, v.y, (2 * kk     > tid), st, sl);
            pair_term(pip, ti, v.z, v.w, (2 * kk + 1 > tid), st, sl);
        }
    }

    for (int off = 32; off > 0; off >>= 1) {
        st += __shfl_down(st, off, 64);
        sl += __shfl_down(sl, off, 64);
    }
    __shared__ float wt[TI / 64], wl[TI / 64];
    const int wave = tid >> 6;
    if ((tid & 63) == 0) { wt[wave] = st; wl[wave] = sl; }
    __syncthreads();
    if (tid == 0) pout[blockIdx.x] = make_float2(wt[0] + wt[1], wl[0] + wl[1]);
}

__global__ __launch_bounds__(256) void rankloss_final(
    const float2* __restrict__ pout, float* __restrict__ out)
{
    const int tid = threadIdx.x;
    double st = 0.0, sl = 0.0;
    for (int b = tid; b < NTILES; b += 256) {
        const float2 v = pout[b];
        st += (double)v.x;
        sl += (double)v.y;
    }
    for (int off = 32; off > 0; off >>= 1) {
        st += __shfl_down(st, off, 64);
        sl += __shfl_down(sl, off, 64);
    }
    __shared__ double wst[4], wsl[4];
    const int wave = tid >> 6;
    if ((tid & 63) == 0) { wst[wave] = st; wsl[wave] = sl; }
    __syncthreads();
    if (tid == 0) {
        double St = 0.0, Sl = 0.0;
        #pragma unroll
        for (int w = 0; w < 4; ++w) { St += wst[w]; Sl += wsl[w]; }
        const double count = 33550336.0;          // C(8192,2)
        const double ln2   = 0.6931471805599453;
        out[0] = (float)((St * ln2 - Sl - (double)B0 * count) / count);
    }
}

extern "C" void kernel_launch(void* const* d_in, const int* in_sizes, int n_in,
                              void* d_out, int out_size, void* d_ws, size_t ws_size,
                              hipStream_t stream) {
    const float* preds = (const float*)d_in[0];
    const float* tgts  = (const float*)d_in[1];
    float2* pout = (float2*)d_ws;   // NTILES float2 = 16.6 KB, fully written by tri

    rankloss_tri<<<NTILES, TI, 0, stream>>>(preds, tgts, pout);
    rankloss_final<<<1, 256, 0, stream>>>(pout, (float*)d_out);
}

// Round 5
// 70.468 us; speedup vs baseline: 2.0114x; 1.0289x over previous
//
#include <hip/hip_runtime.h>

// RankLoss, triangle + poly-log, log2-domain, packed-fp32 inner loop.
//   per unordered pair {i,j}: logsig = min(sd,0) - ln(1+e^{-|d|}),
//   d = p[i]-p[j], sd = (t[i]<t[j] ? d : -d).
// Work in d' = d*log2e: u = e^{-|d|} = 2^{-|d'|}; min(sd,0) = ln2*min(sd',0).
// ln(1+u) ~= B0 + u*q(u) on [0,1] (deg-5, |err|<=1.5e-5); B0*count and ln2
// folded into finalize. count = C(8192,2) analytic (ties measure-zero).
// gfx950 has packed fp32 (v_pk_fma_f32): float2 ext-vectors -> 2 pairs/instr.

#define N 8192
#define TI 128
#define NB (N / TI)                  // 64
#define NTILES (NB * (NB + 1) / 2)   // 2080
#define LOG2E 1.4426950408889634f

#define B0 (-1.084e-05f)
#define B1 ( 0.99923144f)
#define B2 (-0.49021708f)
#define B3 ( 0.28525664f)
#define B4 (-0.13157376f)
#define B5 ( 0.03044704f)

typedef float f2 __attribute__((ext_vector_type(2)));

__global__ __launch_bounds__(TI) void rankloss_tri(
    const float* __restrict__ preds, const float* __restrict__ tgts,
    float2* __restrict__ pout)
{
    __shared__ float sp[TI];   // p*log2e, contiguous -> float4 = 2 packed pairs
    __shared__ float st_[TI];  // t, contiguous (scalar compares only)
    const int tid = threadIdx.x;
    const int u = blockIdx.x;

    // decode triangular tile index: u = jb*(jb+1)/2 + ib, ib <= jb
    int jb = (int)((sqrtf(8.0f * (float)u + 1.0f) - 1.0f) * 0.5f);
    while ((jb + 1) * (jb + 2) / 2 <= u) ++jb;
    while (jb * (jb + 1) / 2 > u) --jb;
    const int ib = u - jb * (jb + 1) / 2;

    const int i  = ib * TI + tid;
    const int j0 = jb * TI;

    sp[tid]  = preds[j0 + tid] * LOG2E;
    st_[tid] = tgts[j0 + tid];
    __syncthreads();

    const float pi = preds[i] * LOG2E;
    const float ti = tgts[i];
    const f2 pip2 = {pi, pi};
    const f2 c5 = {B5, B5}, c4 = {B4, B4}, c3 = {B3, B3}, c2 = {B2, B2}, c1 = {B1, B1};

    f2 sta = {0.f, 0.f}, stb = {0.f, 0.f};   // sum min(sd',0)
    f2 sla = {0.f, 0.f}, slb = {0.f, 0.f};   // sum u*q(u)

    const float4* p4 = (const float4*)sp;
    const float4* t4 = (const float4*)st_;

    if (ib != jb) {
        #pragma unroll 4
        for (int kk = 0; kk < TI / 4; ++kk) {
            const float4 pv = p4[kk];   // uniform addr -> LDS broadcast
            const float4 tv = t4[kk];
            // pairs (4kk, 4kk+1) -> chain a
            {
                f2 pj = {pv.x, pv.y};
                f2 dp = pip2 - pj;                               // v_pk_add (neg)
                f2 uu = {__builtin_amdgcn_exp2f(-fabsf(dp.x)),
                         __builtin_amdgcn_exp2f(-fabsf(dp.y))};
                f2 q = __builtin_elementwise_fma(c5, uu, c4);
                q = __builtin_elementwise_fma(q, uu, c3);
                q = __builtin_elementwise_fma(q, uu, c2);
                q = __builtin_elementwise_fma(q, uu, c1);
                sla = __builtin_elementwise_fma(q, uu, sla);
                f2 sd;
                sd.x = fminf((ti < tv.x) ? dp.x : -dp.x, 0.f);
                sd.y = fminf((ti < tv.y) ? dp.y : -dp.y, 0.f);
                sta += sd;                                       // v_pk_add
            }
            // pairs (4kk+2, 4kk+3) -> chain b
            {
                f2 pj = {pv.z, pv.w};
                f2 dp = pip2 - pj;
                f2 uu = {__builtin_amdgcn_exp2f(-fabsf(dp.x)),
                         __builtin_amdgcn_exp2f(-fabsf(dp.y))};
                f2 q = __builtin_elementwise_fma(c5, uu, c4);
                q = __builtin_elementwise_fma(q, uu, c3);
                q = __builtin_elementwise_fma(q, uu, c2);
                q = __builtin_elementwise_fma(q, uu, c1);
                slb = __builtin_elementwise_fma(q, uu, slb);
                f2 sd;
                sd.x = fminf((ti < tv.z) ? dp.x : -dp.x, 0.f);
                sd.y = fminf((ti < tv.w) ? dp.y : -dp.y, 0.f);
                stb += sd;
            }
        }
    } else {
        // diagonal tile: only j = k > i = tid contributes (3% of tiles; scalar)
        #pragma unroll 4
        for (int k = 0; k < TI; ++k) {
            const float pj = sp[k];
            const float tj = st_[k];
            const float dp = pi - pj;
            float uu = __builtin_amdgcn_exp2f(-fabsf(dp));
            float sd = fminf((ti < tj) ? dp : -dp, 0.f);
            const bool valid = (k > tid);
            uu = valid ? uu : 0.f;
            sd = valid ? sd : 0.f;
            float q = __builtin_fmaf(B5, uu, B4);
            q = __builtin_fmaf(q, uu, B3);
            q = __builtin_fmaf(q, uu, B2);
            q = __builtin_fmaf(q, uu, B1);
            sla.x = __builtin_fmaf(q, uu, sla.x);
            sta.x += sd;
        }
    }

    float stt = sta.x + sta.y + stb.x + stb.y;
    float sll = sla.x + sla.y + slb.x + slb.y;
    for (int off = 32; off > 0; off >>= 1) {
        stt += __shfl_down(stt, off, 64);
        sll += __shfl_down(sll, off, 64);
    }
    __shared__ float wt[TI / 64], wl[TI / 64];
    const int wave = tid >> 6;
    if ((tid & 63) == 0) { wt[wave] = stt; wl[wave] = sll; }
    __syncthreads();
    if (tid == 0) pout[blockIdx.x] = make_float2(wt[0] + wt[1], wl[0] + wl[1]);
}

__global__ __launch_bounds__(256) void rankloss_final(
    const float2* __restrict__ pout, float* __restrict__ out)
{
    const int tid = threadIdx.x;
    double st = 0.0, sl = 0.0;
    for (int b = tid; b < NTILES; b += 256) {
        const float2 v = pout[b];
        st += (double)v.x;
        sl += (double)v.y;
    }
    for (int off = 32; off > 0; off >>= 1) {
        st += __shfl_down(st, off, 64);
        sl += __shfl_down(sl, off, 64);
    }
    __shared__ double wst[4], wsl[4];
    const int wave = tid >> 6;
    if ((tid & 63) == 0) { wst[wave] = st; wsl[wave] = sl; }
    __syncthreads();
    if (tid == 0) {
        double St = 0.0, Sl = 0.0;
        #pragma unroll
        for (int w = 0; w < 4; ++w) { St += wst[w]; Sl += wsl[w]; }
        const double count = 33550336.0;          // C(8192,2)
        const double ln2   = 0.6931471805599453;
        out[0] = (float)((St * ln2 - Sl - (double)B0 * count) / count);
    }
}

extern "C" void kernel_launch(void* const* d_in, const int* in_sizes, int n_in,
                              void* d_out, int out_size, void* d_ws, size_t ws_size,
                              hipStream_t stream) {
    const float* preds = (const float*)d_in[0];
    const float* tgts  = (const float*)d_in[1];
    float2* pout = (float2*)d_ws;   // NTILES float2 = 16.6 KB, fully written by tri

    rankloss_tri<<<NTILES, TI, 0, stream>>>(preds, tgts, pout);
    rankloss_final<<<1, 256, 0, stream>>>(pout, (float*)d_out);
}